// Round 1
// baseline (1222.110 us; speedup 1.0000x reference)
//
#include <hip/hip_runtime.h>
#include <math.h>

#define MDIM 20
#define ODIM 512
#define LSTR 21            // padded LDS row stride (gcd(21,32)=1 -> no 8-way conflicts)
#define ROWS_PER_BLOCK 64

typedef float f4 __attribute__((ext_vector_type(4)));

// ---------------------------------------------------------------------------
// Kernel 1: Householder QR of (weight[512][20] + 1e-8), LAPACK sgeqf2/sorg2r
// convention (beta = -sign(alpha)*norm), single workgroup. Writes
// Qt[20][512] (row-major, i.e. Qt[c*512 + r] = Q[r][c]) into workspace.
// ---------------------------------------------------------------------------
__global__ __launch_bounds__(256) void qr_kernel(const float* __restrict__ w,
                                                 float* __restrict__ qt) {
  __shared__ float A[ODIM * LSTR];
  __shared__ float tau_s[MDIM];
  __shared__ float wc[MDIM];
  __shared__ float red[4];
  const int tid = threadIdx.x;
  const int lane = tid & 63;
  const int wave = tid >> 6;

  // Load + add 1e-8 (row-major [512][20] -> padded LDS)
  for (int i = tid; i < ODIM * MDIM; i += 256) {
    int r = i / MDIM, c = i - r * MDIM;
    A[r * LSTR + c] = w[i] + 1e-8f;
  }
  __syncthreads();

  // ---- Factorization (sgeqf2): v's stored below diag in A ----
  for (int j = 0; j < MDIM; ++j) {
    // xnorm^2 over rows j+1..511 of column j
    float s = 0.f;
    for (int r = j + 1 + tid; r < ODIM; r += 256) {
      float v = A[r * LSTR + j];
      s += v * v;
    }
    #pragma unroll
    for (int off = 32; off > 0; off >>= 1) s += __shfl_down(s, off, 64);
    if (lane == 0) red[wave] = s;
    __syncthreads();
    float xn2 = red[0] + red[1] + red[2] + red[3];
    float alpha = A[j * LSTR + j];
    float tau, vinv;
    if (xn2 == 0.f) {                 // LAPACK dlarfg special case: H = I
      tau = 0.f;
      vinv = 0.f;
    } else {
      float beta = -copysignf(sqrtf(alpha * alpha + xn2), alpha);
      tau = (beta - alpha) / beta;
      vinv = 1.f / (alpha - beta);
    }
    if (tid == 0) tau_s[j] = tau;
    // scale v (v_j = 1 implicit)
    for (int r = j + 1 + tid; r < ODIM; r += 256) A[r * LSTR + j] *= vinv;
    __syncthreads();
    // w_c = tau * (A[j][c] + sum_{r>j} v_r A[r][c]),  c = j+1..19
    for (int c = j + 1 + wave; c < MDIM; c += 4) {
      float acc = 0.f;
      for (int r = j + 1 + lane; r < ODIM; r += 64)
        acc += A[r * LSTR + j] * A[r * LSTR + c];
      #pragma unroll
      for (int off = 32; off > 0; off >>= 1) acc += __shfl_down(acc, off, 64);
      if (lane == 0) wc[c] = tau * (A[j * LSTR + c] + acc);
    }
    __syncthreads();
    // trailing update, rows r>j only (row j holds R, never read again)
    for (int c = j + 1; c < MDIM; ++c) {
      float wcc = wc[c];
      for (int r = j + 1 + tid; r < ODIM; r += 256)
        A[r * LSTR + c] -= A[r * LSTR + j] * wcc;
    }
    __syncthreads();
  }

  // ---- Form Q in place (sorg2r), i = 19 down to 0 ----
  for (int i = MDIM - 1; i >= 0; --i) {
    float tau = tau_s[i];
    // w_c = tau * (A[i][c] + sum_{r>i} v_r A[r][c]),  c = i+1..19
    for (int c = i + 1 + wave; c < MDIM; c += 4) {
      float acc = 0.f;
      for (int r = i + 1 + lane; r < ODIM; r += 64)
        acc += A[r * LSTR + i] * A[r * LSTR + c];
      #pragma unroll
      for (int off = 32; off > 0; off >>= 1) acc += __shfl_down(acc, off, 64);
      if (lane == 0) wc[c] = tau * (A[i * LSTR + c] + acc);
    }
    __syncthreads();
    // apply H_i to columns c>i, rows r>=i (v_i = 1)
    for (int c = i + 1; c < MDIM; ++c) {
      float wcc = wc[c];
      for (int r = i + tid; r < ODIM; r += 256) {
        float v = (r == i) ? 1.f : A[r * LSTR + i];
        A[r * LSTR + c] -= v * wcc;
      }
    }
    __syncthreads();
    // column i becomes Q column: scale by -tau, diag = 1-tau, zeros above
    for (int r = tid; r < ODIM; r += 256) {
      float val;
      if (r < i) val = 0.f;
      else if (r == i) val = 1.f - tau;
      else val = -tau * A[r * LSTR + i];
      A[r * LSTR + i] = val;
    }
    __syncthreads();
  }

  // write transposed: Qt[c][r] = Q[r][c]
  for (int idx = tid; idx < MDIM * ODIM; idx += 256) {
    int c = idx >> 9, r = idx & 511;
    qt[idx] = A[r * LSTR + c];
  }
}

// ---------------------------------------------------------------------------
// Kernel 2: out[b][o] = sum_m input[b][m] * Qt[m][o]
// 256 threads, 64 rows/block. Thread t owns output float4 column (t&127);
// Q fragment (20 float4) lives in registers; input tile in LDS (broadcast).
// ---------------------------------------------------------------------------
__global__ __launch_bounds__(256, 4) void matmul_kernel(
    const float* __restrict__ in, const float* __restrict__ qt,
    float* __restrict__ out, int batch) {
  __shared__ f4 tile4[ROWS_PER_BLOCK * MDIM / 4];  // 64 rows * 20 fl = 5 KiB
  const int tid = threadIdx.x;
  const int oq = tid & 127;   // float4 index within the 512-wide output row
  const int grp = tid >> 7;   // 0 or 1: which half of the row tile
  const int base = blockIdx.x * ROWS_PER_BLOCK;
  int nrows = batch - base;
  if (nrows > ROWS_PER_BLOCK) nrows = ROWS_PER_BLOCK;

  // stage input tile (coalesced float4; base*20 floats = base*80 B, 16B-aligned)
  const f4* in4 = (const f4*)(in + (size_t)base * MDIM);
  const int nf4 = nrows * MDIM / 4;  // 20 floats/row -> always mult of 4
  for (int i = tid; i < nf4; i += 256) tile4[i] = in4[i];

  // Q fragment: 20 x float4 in registers (L1/L2-hit after first block)
  const f4* qt4 = (const f4*)qt;
  f4 qv[MDIM];
  #pragma unroll
  for (int m = 0; m < MDIM; ++m) qv[m] = qt4[m * 128 + oq];
  __syncthreads();

  f4* out4 = (f4*)out;
  const float* tile = (const float*)tile4;
  #pragma unroll 1
  for (int it = 0; it < ROWS_PER_BLOCK / 2; ++it) {
    const int lr = grp * (ROWS_PER_BLOCK / 2) + it;
    if (lr >= nrows) break;
    const f4* row4 = (const f4*)(tile + lr * MDIM);
    f4 xv[5];
    #pragma unroll
    for (int k = 0; k < 5; ++k) xv[k] = row4[k];  // broadcast LDS reads
    f4 acc = (f4)(0.f);
    #pragma unroll
    for (int m = 0; m < MDIM; ++m) {
      float x = xv[m / 4][m % 4];
      acc += x * qv[m];
    }
    __builtin_nontemporal_store(acc, &out4[(size_t)(base + lr) * 128 + oq]);
  }
}

extern "C" void kernel_launch(void* const* d_in, const int* in_sizes, int n_in,
                              void* d_out, int out_size, void* d_ws, size_t ws_size,
                              hipStream_t stream) {
  const float* input = (const float*)d_in[0];   // [batch, 20] fp32
  const float* weight = (const float*)d_in[1];  // [512, 20] fp32
  float* out = (float*)d_out;                   // [batch, 512] fp32
  float* qt = (float*)d_ws;                     // Qt[20][512] scratch (40 KiB)
  const int batch = in_sizes[0] / MDIM;

  qr_kernel<<<1, 256, 0, stream>>>(weight, qt);
  const int blocks = (batch + ROWS_PER_BLOCK - 1) / ROWS_PER_BLOCK;
  matmul_kernel<<<blocks, 256, 0, stream>>>(input, qt, out, batch);
}